// Round 1
// baseline (188.680 us; speedup 1.0000x reference)
//
#include <hip/hip_runtime.h>

#define DEV __device__ __forceinline__

constexpr int H  = 128;
constexpr int BP = 32;        // B*P
constexpr int NR = 2048;      // BP*64 rows

// workspace layout (float offsets)
constexpr int WH_OFF    = 0;                       // [2048][128] weapon_h
constexpr int TH_OFF    = WH_OFF + NR*H;           // [2048][128] target_h
constexpr int WHS_OFF   = TH_OFF + NR*H;           // [32][128] weapon_h.sum(axis=2)
constexpr int THS_OFF   = WHS_OFF + BP*H;          // [32][128]
constexpr int V1_OFF    = THS_OFF + BP*H;          // [128]
constexpr int C0_OFF    = V1_OFF + H;              // [128]
constexpr int WT1_OFF   = C0_OFF + H;              // [128][640]  eaT|waT|whh_wT
constexpr int WT2_OFF   = WT1_OFF + 128*640;       // [128][640]  ebT|taT|whh_tT
constexpr int WCT_OFF   = WT2_OFF + 128*640;       // [128][128]
constexpr int TCT_OFF   = WCT_OFF + 128*128;
constexpr int WIHWT_OFF = TCT_OFF + 128*128;       // [128][384]
constexpr int WIHTT_OFF = WIHWT_OFF + 128*384;
constexpr int WBT_OFF   = WIHTT_OFF + 128*384;     // [128][128]
constexpr int TBT_OFF   = WBT_OFF + 128*128;
constexpr int OUT1_OFF  = TBT_OFF + 128*128;       // [2048][640]  A|WA|ghw
constexpr int OUT2_OFF  = OUT1_OFF + NR*640;       // [2048][640]  Bt|TA|ght
constexpr int ESW_OFF   = OUT2_OFF + NR*640;       // [2048][128] edge sum over t
constexpr int ESTP_OFF  = ESW_OFF + NR*H;          // [8][2048][128] partial sums over w
constexpr int MSGW_OFF  = ESTP_OFF + 8*NR*H;       // [2048][128]
constexpr int MSGT_OFF  = MSGW_OFF + NR*H;
constexpr int GIW_OFF   = MSGT_OFF + NR*H;         // [2048][384]
constexpr int GIT_OFF   = GIW_OFF + NR*384;
constexpr int WBV_OFF   = GIT_OFF + NR*384;        // [32][128]
constexpr int TBV_OFF   = WBV_OFF + BP*H;          // [32][128]

DEV float fast_tanh(float x) {
  float e = __builtin_amdgcn_exp2f(x * 2.8853900817779268f);  // exp(2x)
  return fmaf(-2.0f, __builtin_amdgcn_rcpf(e + 1.0f), 1.0f);
}
DEV float fast_sigmoid(float x) {
  float e = __builtin_amdgcn_exp2f(x * -1.4426950408889634f); // exp(-x)
  return __builtin_amdgcn_rcpf(1.0f + e);
}

// ---------------- K1: input projections + weight transposes ----------------
__global__ __launch_bounds__(256) void k1_proj_transpose(
    const float* __restrict__ wf, const float* __restrict__ tf,
    const float* __restrict__ wp_w, const float* __restrict__ wp_b,
    const float* __restrict__ tp_w, const float* __restrict__ tp_b,
    const float* __restrict__ eu_w, const float* __restrict__ wm_w,
    const float* __restrict__ tm_w,
    const float* __restrict__ whh_w, const float* __restrict__ whh_t,
    const float* __restrict__ wih_w, const float* __restrict__ wih_t,
    float* __restrict__ ws)
{
  int bid = blockIdx.x, tid = threadIdx.x;
  if (bid < 2048) {
    int gid = bid*256 + tid;
    int m = gid >> 7;       // 0..4095
    int j = gid & 127;
    int side = m >> 11;
    int n = m & 2047;
    const float* F  = side ? tf : wf;
    const float* Pw = side ? tp_w : wp_w;
    const float* Pb = side ? tp_b : wp_b;
    float4 x  = *(const float4*)&F[n*4];
    float4 wv = *(const float4*)&Pw[j*4];
    float v = x.x*wv.x + x.y*wv.y + x.z*wv.z + x.w*wv.w + Pb[j];
    ws[(side ? TH_OFF : WH_OFF) + n*H + j] = v;
  } else {
    int idx = (bid - 2048)*256 + tid;
    if (idx < 131072) {                  // 8 transposes of 128x128 slices
      int which = idx >> 14;
      int r = idx & 16383;
      int k = r >> 7, j = r & 127;
      float v; float* dst;
      switch (which) {
        case 0: v = eu_w[j*384 + k];        dst = ws + WT1_OFF + k*640 + j;       break;
        case 1: v = wm_w[j*384 + k];        dst = ws + WT1_OFF + k*640 + 128 + j; break;
        case 2: v = eu_w[j*384 + 128 + k];  dst = ws + WT2_OFF + k*640 + j;       break;
        case 3: v = tm_w[j*384 + k];        dst = ws + WT2_OFF + k*640 + 128 + j; break;
        case 4: v = wm_w[j*384 + 256 + k];  dst = ws + WCT_OFF + k*128 + j;       break;
        case 5: v = tm_w[j*384 + 256 + k];  dst = ws + TCT_OFF + k*128 + j;       break;
        case 6: v = wm_w[j*384 + 128 + k];  dst = ws + WBT_OFF + k*128 + j;       break;
        default:v = tm_w[j*384 + 128 + k];  dst = ws + TBT_OFF + k*128 + j;       break;
      }
      *dst = v;
    } else {                             // 4 transposes of 384x128 GRU weights
      int idx2 = idx - 131072;
      int which = idx2 / 49152;
      int r = idx2 % 49152;
      int k = r / 384, j = r % 384;
      float v; float* dst;
      switch (which) {
        case 0: v = whh_w[j*128 + k]; dst = ws + WT1_OFF + k*640 + 256 + j; break;
        case 1: v = whh_t[j*128 + k]; dst = ws + WT2_OFF + k*640 + 256 + j; break;
        case 2: v = wih_w[j*128 + k]; dst = ws + WIHWT_OFF + k*384 + j;     break;
        default:v = wih_t[j*128 + k]; dst = ws + WIHTT_OFF + k*384 + j;     break;
      }
      *dst = v;
    }
  }
}

// ---------------- K2: per-(b,p) sums of wh/th, and v1/c0 vectors ----------------
__global__ __launch_bounds__(256) void k2_sums(
    float* __restrict__ ws,
    const float* __restrict__ ep_w, const float* __restrict__ ep_b,
    const float* __restrict__ eu_w, const float* __restrict__ eu_b)
{
  int bid = blockIdx.x, tid = threadIdx.x;
  if (bid < 32) {
    int j = tid & 127, half = tid >> 7;
    const float* src = ws + (half ? TH_OFF : WH_OFF) + bid*64*H + j;
    float s = 0.f;
    #pragma unroll 8
    for (int t = 0; t < 64; ++t) s += src[t*H];
    ws[(half ? THS_OFF : WHS_OFF) + bid*H + j] = s;
  } else if (tid < 128) {
    int j = tid;
    float s1 = 0.f, s0 = 0.f;
    for (int k = 0; k < 128; ++k) {
      float ec = eu_w[j*384 + 256 + k];
      s1 = fmaf(ec, ep_w[k], s1);
      s0 = fmaf(ec, ep_b[k], s0);
    }
    ws[V1_OFF + j] = s1;
    ws[C0_OFF + j] = s0 + eu_b[j];
  }
}

// ---------------- generic 32x128-tile fp32 GEMM core (K=128) ----------------
#define FMA4(A, s, Wv) do { A.x = fmaf(s, Wv.x, A.x); A.y = fmaf(s, Wv.y, A.y); \
                            A.z = fmaf(s, Wv.z, A.z); A.w = fmaf(s, Wv.w, A.w); } while (0)

DEV void stage_x_direct(float* Xs, const float* __restrict__ X, int row0, int tid) {
  const float* src = X + row0*128;
  #pragma unroll
  for (int q = 0; q < 4; ++q) {
    int idx = q*1024 + tid*4;
    *(float4*)&Xs[idx] = *(const float4*)&src[idx];
  }
}

DEV void stage_x_sum8(float* Xs, const float* __restrict__ base, int row0, int tid) {
  #pragma unroll
  for (int q = 0; q < 4; ++q) {
    int idx = q*1024 + tid*4;
    float4 s = *(const float4*)&base[row0*128 + idx];
    #pragma unroll
    for (int wt = 1; wt < 8; ++wt) {
      float4 v = *(const float4*)&base[wt*(NR*H) + row0*128 + idx];
      s.x += v.x; s.y += v.y; s.z += v.z; s.w += v.w;
    }
    *(float4*)&Xs[idx] = s;
  }
}

DEV void gemm_core(const float* __restrict__ Wt, int ldw, int j0,
                   const float* Xs, float* Ws, int tid, float4 acc[4])
{
  const int tc = tid & 31, tr = tid >> 5;
  const int jj = tc*4, r0 = tr*4;
  #pragma unroll
  for (int i = 0; i < 4; ++i) acc[i] = make_float4(0.f, 0.f, 0.f, 0.f);
  for (int kc = 0; kc < 128; kc += 32) {
    __syncthreads();
    #pragma unroll
    for (int q = 0; q < 4; ++q) {
      int idx = q*1024 + tid*4;
      int kk = idx >> 7, j = idx & 127;
      *(float4*)&Ws[idx] = *(const float4*)&Wt[(kc+kk)*ldw + j0 + j];
    }
    __syncthreads();
    #pragma unroll
    for (int kk = 0; kk < 32; kk += 4) {
      float4 w0 = *(const float4*)&Ws[(kk+0)*128 + jj];
      float4 w1 = *(const float4*)&Ws[(kk+1)*128 + jj];
      float4 w2 = *(const float4*)&Ws[(kk+2)*128 + jj];
      float4 w3 = *(const float4*)&Ws[(kk+3)*128 + jj];
      #pragma unroll
      for (int rr = 0; rr < 4; ++rr) {
        float4 xq = *(const float4*)&Xs[(r0+rr)*128 + kc + kk];
        FMA4(acc[rr], xq.x, w0);
        FMA4(acc[rr], xq.y, w1);
        FMA4(acc[rr], xq.z, w2);
        FMA4(acc[rr], xq.w, w3);
      }
    }
  }
}

// ---------------- K3: OUT1 = wh @ [ea|wa|whh_w]^T, OUT2 = th @ [...], + WBV/TBV ----
__global__ __launch_bounds__(256) void k3_gemm1(float* __restrict__ ws)
{
  __shared__ float Xs[32*128];
  __shared__ float Wsh[32*128];
  int bid = blockIdx.x, tid = threadIdx.x;
  const int tc = tid & 31, tr = tid >> 5;
  const int jj = tc*4, r0 = tr*4;
  float4 acc[4];
  if (bid < 640) {
    int side = bid >= 320;
    int b2 = bid - (side ? 320 : 0);
    int rt = b2 & 63, ct = b2 >> 6;      // 64 row tiles x 5 col tiles
    int row0 = rt*32;
    stage_x_direct(Xs, ws + (side ? TH_OFF : WH_OFF), row0, tid);
    gemm_core(ws + (side ? WT2_OFF : WT1_OFF), 640, ct*128, Xs, Wsh, tid, acc);
    float* C = ws + (side ? OUT2_OFF : OUT1_OFF);
    #pragma unroll
    for (int rr = 0; rr < 4; ++rr)
      *(float4*)&C[(row0+r0+rr)*640 + ct*128 + jj] = acc[rr];
  } else {
    int which = bid - 640;               // 0: WBV = THS@wb^T, 1: TBV = WHS@tb^T
    stage_x_direct(Xs, ws + (which ? WHS_OFF : THS_OFF), 0, tid);
    gemm_core(ws + (which ? TBT_OFF : WBT_OFF), 128, 0, Xs, Wsh, tid, acc);
    float* C = ws + (which ? TBV_OFF : WBV_OFF);
    #pragma unroll
    for (int rr = 0; rr < 4; ++rr)
      *(float4*)&C[(r0+rr)*128 + jj] = acc[rr];
  }
}

// ---------------- K4: edge tanh + both edge sums ----------------
__global__ __launch_bounds__(256) void k4_edge(
    const float* __restrict__ ef, float* __restrict__ ws, float* __restrict__ out)
{
  __shared__ float e_lds[8*64];
  __shared__ float red[2][8][128];
  int bid = blockIdx.x, tid = threadIdx.x;
  int bp = bid >> 3, wt = bid & 7;
  int j = tid & 127, tsel = tid >> 7;
  float v1j = ws[V1_OFF + j], c0j = ws[C0_OFF + j];
  {
    const float* esrc = ef + bp*4096 + wt*512;
    *(float2*)&e_lds[tid*2] = *(const float2*)&esrc[tid*2];
  }
  float a_reg[8];
  #pragma unroll
  for (int w = 0; w < 8; ++w)
    a_reg[w] = ws[OUT1_OFF + (bp*64 + wt*8 + w)*640 + j];
  __syncthreads();
  float tsum[8] = {0,0,0,0,0,0,0,0};
  float* edst = out + 524288 + (bp*64 + wt*8)*64*128;
  const float* btp = ws + OUT2_OFF + bp*64*640 + j;
  float* pdst = ws + ESTP_OFF + wt*(NR*H) + bp*64*128 + j;
  for (int i = 0; i < 32; ++i) {
    int t = 2*i + tsel;
    float base = btp[t*640] + c0j;
    float wsum = 0.f;
    #pragma unroll
    for (int w = 0; w < 8; ++w) {
      float ev = e_lds[w*64 + t];
      float pre = a_reg[w] + fmaf(ev, v1j, base);
      float hv = fast_tanh(pre);
      edst[(w*64 + t)*128 + j] = hv;
      tsum[w] += hv;
      wsum += hv;
    }
    pdst[t*128] = wsum;
  }
  #pragma unroll
  for (int w = 0; w < 8; ++w) red[tsel][w][j] = tsum[w];
  __syncthreads();
  if (tsel == 0) {
    #pragma unroll
    for (int w = 0; w < 8; ++w)
      ws[ESW_OFF + (bp*64 + wt*8 + w)*128 + j] = red[0][w][j] + red[1][w][j];
  }
}

// ---------------- K5: msgs = edge_sum @ wc^T + T*WA + WBv + T*bias ----------------
__global__ __launch_bounds__(256) void k5_gemm2(
    float* __restrict__ ws, const float* __restrict__ wm_b, const float* __restrict__ tm_b)
{
  __shared__ float Xs[32*128];
  __shared__ float Wsh[32*128];
  int bid = blockIdx.x, tid = threadIdx.x;
  int side = bid >> 6, rt = bid & 63;
  int row0 = rt*32;
  const int tc = tid & 31, tr = tid >> 5;
  const int jj = tc*4, r0 = tr*4;
  if (side == 0) stage_x_direct(Xs, ws + ESW_OFF, row0, tid);
  else           stage_x_sum8(Xs, ws + ESTP_OFF, row0, tid);
  float4 acc[4];
  gemm_core(ws + (side ? TCT_OFF : WCT_OFF), 128, 0, Xs, Wsh, tid, acc);
  const float* OUTx = ws + (side ? OUT2_OFF : OUT1_OFF);
  const float* BV   = ws + (side ? TBV_OFF : WBV_OFF);
  const float* mb   = side ? tm_b : wm_b;
  float* MSG        = ws + (side ? MSGT_OFF : MSGW_OFF);
  float4 b4 = *(const float4*)&mb[jj];
  #pragma unroll
  for (int rr = 0; rr < 4; ++rr) {
    int n = row0 + r0 + rr;
    float4 wa4 = *(const float4*)&OUTx[n*640 + 128 + jj];
    float4 bv4 = *(const float4*)&BV[(n >> 6)*128 + jj];
    float4 r;
    r.x = acc[rr].x + 64.f*wa4.x + bv4.x + 64.f*b4.x;
    r.y = acc[rr].y + 64.f*wa4.y + bv4.y + 64.f*b4.y;
    r.z = acc[rr].z + 64.f*wa4.z + bv4.z + 64.f*b4.z;
    r.w = acc[rr].w + 64.f*wa4.w + bv4.w + 64.f*b4.w;
    *(float4*)&MSG[n*128 + jj] = r;
  }
}

// ---------------- K6: gi = msgs @ w_ih^T ----------------
__global__ __launch_bounds__(256) void k6_gemm3(float* __restrict__ ws)
{
  __shared__ float Xs[32*128];
  __shared__ float Wsh[32*128];
  int bid = blockIdx.x, tid = threadIdx.x;
  int side = bid >= 192;
  int b2 = bid - (side ? 192 : 0);
  int rt = b2 & 63, ct = b2 >> 6;       // 64 row tiles x 3 col tiles
  int row0 = rt*32;
  const int tc = tid & 31, tr = tid >> 5;
  const int jj = tc*4, r0 = tr*4;
  stage_x_direct(Xs, ws + (side ? MSGT_OFF : MSGW_OFF), row0, tid);
  float4 acc[4];
  gemm_core(ws + (side ? WIHTT_OFF : WIHWT_OFF), 384, ct*128, Xs, Wsh, tid, acc);
  float* C = ws + (side ? GIT_OFF : GIW_OFF);
  #pragma unroll
  for (int rr = 0; rr < 4; ++rr)
    *(float4*)&C[(row0+r0+rr)*384 + ct*128 + jj] = acc[rr];
}

// ---------------- K7: GRU gates (elementwise) ----------------
__global__ __launch_bounds__(256) void k7_gru(
    const float* __restrict__ ws, float* __restrict__ out,
    const float* __restrict__ bih_w, const float* __restrict__ bhh_w,
    const float* __restrict__ bih_t, const float* __restrict__ bhh_t)
{
  int gid = blockIdx.x*256 + threadIdx.x;
  int m = gid >> 7, j = gid & 127;
  int side = m >> 11, n = m & 2047;
  const float* GI = ws + (side ? GIT_OFF : GIW_OFF) + n*384;
  const float* GH = ws + (side ? OUT2_OFF : OUT1_OFF) + n*640 + 256;
  const float* Hv = ws + (side ? TH_OFF : WH_OFF) + n*128;
  const float* bi = side ? bih_t : bih_w;
  const float* bh = side ? bhh_t : bhh_w;
  float gir = GI[j]       + bi[j];
  float giz = GI[128 + j] + bi[128 + j];
  float gin = GI[256 + j] + bi[256 + j];
  float ghr = GH[j]       + bh[j];
  float ghz = GH[128 + j] + bh[128 + j];
  float ghn = GH[256 + j] + bh[256 + j];
  float r  = fast_sigmoid(gir + ghr);
  float z  = fast_sigmoid(giz + ghz);
  float nn = fast_tanh(gin + r*ghn);
  float h  = Hv[j];
  out[side*262144 + n*128 + j] = (1.f - z)*nn + z*h;
}

extern "C" void kernel_launch(void* const* d_in, const int* in_sizes, int n_in,
                              void* d_out, int out_size, void* d_ws, size_t ws_size,
                              hipStream_t stream)
{
  const float* wf    = (const float*)d_in[0];
  const float* tf    = (const float*)d_in[1];
  const float* ef    = (const float*)d_in[2];
  const float* wp_w  = (const float*)d_in[3];
  const float* wp_b  = (const float*)d_in[4];
  const float* tp_w  = (const float*)d_in[5];
  const float* tp_b  = (const float*)d_in[6];
  const float* ep_w  = (const float*)d_in[7];
  const float* ep_b  = (const float*)d_in[8];
  const float* eu_w  = (const float*)d_in[9];
  const float* eu_b  = (const float*)d_in[10];
  const float* wm_w  = (const float*)d_in[11];
  const float* wm_b  = (const float*)d_in[12];
  const float* tm_w  = (const float*)d_in[13];
  const float* tm_b  = (const float*)d_in[14];
  const float* wih_w = (const float*)d_in[15];
  const float* whh_w = (const float*)d_in[16];
  const float* bih_w = (const float*)d_in[17];
  const float* bhh_w = (const float*)d_in[18];
  const float* wih_t = (const float*)d_in[19];
  const float* whh_t = (const float*)d_in[20];
  const float* bih_t = (const float*)d_in[21];
  const float* bhh_t = (const float*)d_in[22];
  float* ws  = (float*)d_ws;
  float* out = (float*)d_out;

  hipLaunchKernelGGL(k1_proj_transpose, dim3(3328), dim3(256), 0, stream,
                     wf, tf, wp_w, wp_b, tp_w, tp_b, eu_w, wm_w, tm_w,
                     whh_w, whh_t, wih_w, wih_t, ws);
  hipLaunchKernelGGL(k2_sums,  dim3(33),   dim3(256), 0, stream, ws, ep_w, ep_b, eu_w, eu_b);
  hipLaunchKernelGGL(k3_gemm1, dim3(642),  dim3(256), 0, stream, ws);
  hipLaunchKernelGGL(k4_edge,  dim3(256),  dim3(256), 0, stream, ef, ws, out);
  hipLaunchKernelGGL(k5_gemm2, dim3(128),  dim3(256), 0, stream, ws, wm_b, tm_b);
  hipLaunchKernelGGL(k6_gemm3, dim3(384),  dim3(256), 0, stream, ws);
  hipLaunchKernelGGL(k7_gru,   dim3(2048), dim3(256), 0, stream, ws, out,
                     bih_w, bhh_w, bih_t, bhh_t);
}